// Round 11
// baseline (398.914 us; speedup 1.0000x reference)
//
#include <hip/hip_runtime.h>
#include <math.h>

#define NV 10000
#define ND 300
#define NB 64
#define NL 128
#define CFv 5.0f
#define EPSV 1e-8f

// ws float-index layout (~6.3 MB used; ws >= 1.6 GB per harness fill)
#define WS_CTX   0        // 300 floats
#define WS_CN    300      // 1 float
#define WS_CNT   301      // 1 int (active-row count)
#define WS_A     320      // 10000 floats: CF*lam*cos
#define WS_B     10320    // 10000 floats: CF*(1-lam)*aff
#define WS_ROWS  20320    // 8192 ints (compacted, SORTED active row ids b*128+l)
#define WS_S     28512    // 8192 floats (softmax denominators)
#define WS_CUM   36704    // 65 ints (per-batch prefix sums)
#define WS_WTG   36800    // bf16 WtG[304][10112] (byte off 147200, 16B aligned)

// k_main config
#define KR    128         // K-slice per block
#define WTGLD 10112       // padded WtG row length (= 79*128)
#define NKR   79          // ceil(10000/128)
#define GMB   8           // batches per block (8 M-groups)
#define NTI   19          // 19 n-tiles of 16 cover 304
#define MT    32          // rows per M-tile
#define MTOT  1024        // max rows per block (GMB*NL)

typedef __attribute__((ext_vector_type(8))) __bf16 bf16x8;
typedef __attribute__((ext_vector_type(4))) float f32x4;

static __device__ __forceinline__ unsigned short f2bf(float x) {
  union { float f; unsigned u; } v; v.f = x;
  unsigned r = v.u + 0x7fffu + ((v.u >> 16) & 1u);
  return (unsigned short)(r >> 16);
}

__global__ __launch_bounds__(256) void k_init(float* __restrict__ out, float* __restrict__ wsf) {
  int g = blockIdx.x * 256 + threadIdx.x;
  if (g < NB * ND) out[g] = 0.f;
  if (g < 302) wsf[g] = 0.f;
}

#define CSL 4
__global__ __launch_bounds__(320) void k_context(const int* __restrict__ clist,
                                                 const int* __restrict__ clen,
                                                 const float* __restrict__ embed,
                                                 float* __restrict__ wsf) {
  __shared__ int kl[NL];
  int b = blockIdx.x / CSL, sl = blockIdx.x % CSL;
  int d = threadIdx.x;
  int len = clen[b];
  if (d < NL) kl[d] = clist[b * NL + d];
  __syncthreads();
  if (d >= ND) return;
  float acc = 0.f;
  for (int l = sl; l < len; l += CSL)
    acc += embed[(long)kl[l] * ND + d];
  float dn = (float)(len > 0 ? len : 1);
  atomicAdd(&wsf[WS_CTX + d], acc * (1.0f / NB) / dn);
}

__global__ __launch_bounds__(320) void k_cn(float* __restrict__ wsf) {
  __shared__ float red[5];
  int t = threadIdx.x;
  float x = (t < ND) ? wsf[WS_CTX + t] : 0.f;
  float s = x * x;
  #pragma unroll
  for (int o = 32; o; o >>= 1) s += __shfl_xor(s, o);
  if ((t & 63) == 0) red[t >> 6] = s;
  __syncthreads();
  if (t == 0) {
    float tot = 0.f;
    #pragma unroll
    for (int i = 0; i < 5; ++i) tot += red[i];
    wsf[WS_CN] = sqrtf(tot);
  }
}

// per-concept |cos| then fused constants A = CF*lam*cos, B = CF*(1-lam)*aff
__global__ __launch_bounds__(256) void k_cos(const float* __restrict__ cw,
                                             const float* __restrict__ lam,
                                             const float* __restrict__ aff,
                                             float* __restrict__ wsf) {
  int wid = threadIdx.x >> 6, lane = threadIdx.x & 63;
  int v = blockIdx.x * 4 + wid;
  const float* row = cw + (long)v * ND;
  float dot = 0.f, rn2 = 0.f;
  for (int d = lane; d < ND; d += 64) {
    float w = row[d], c = wsf[WS_CTX + d];
    dot += w * c;
    rn2 += w * w;
  }
  #pragma unroll
  for (int o = 32; o; o >>= 1) { dot += __shfl_xor(dot, o); rn2 += __shfl_xor(rn2, o); }
  if (lane == 0) {
    float cn = wsf[WS_CN];
    float cosv = fabsf(dot) / fmaxf(cn * sqrtf(rn2), EPSV);
    float lv = lam[v];
    wsf[WS_A + v] = CFv * lv * cosv;
    wsf[WS_B + v] = CFv * (1.f - lv) * aff[v];
  }
}

// transpose concept_w -> bf16 WtG[304][WTGLD] in ws (zero-padded rows/cols)
__global__ __launch_bounds__(256) void k_wt(const float* __restrict__ cw, float* __restrict__ wsf) {
  __shared__ unsigned short T[304][68];
  int tid = threadIdx.x;
  int v0 = blockIdx.x * 64;
  for (int q = tid; q < 304 * 68 / 2; q += 256) ((unsigned*)&T[0][0])[q] = 0u;
  __syncthreads();
  const float4* cw4 = (const float4*)cw;
  for (int q = tid; q < 64 * 75; q += 256) {
    int r = q / 75, p = q - r * 75;
    int v = v0 + r;
    if (v < NV) {
      float4 w = cw4[(long)v * 75 + p];
      T[4 * p + 0][r] = f2bf(w.x);
      T[4 * p + 1][r] = f2bf(w.y);
      T[4 * p + 2][r] = f2bf(w.z);
      T[4 * p + 3][r] = f2bf(w.w);
    }
  }
  __syncthreads();
  unsigned short* wtg = (unsigned short*)(wsf + WS_WTG);
  for (int q = tid; q < 304 * 16; q += 256) {
    int n = q >> 4, rp = q & 15;
    *(ushort4*)&wtg[(long)n * WTGLD + v0 + 4 * rp] = *(const ushort4*)&T[n][4 * rp];
  }
}

// parallel compaction + cum store
__global__ __launch_bounds__(256) void k_compact(const int* __restrict__ clen, int* __restrict__ wsi) {
  __shared__ int cum[NB + 1];
  int tid = threadIdx.x;
  if (tid < 64) {
    int ln = clen[tid]; ln = min(max(ln, 0), NL);
    int s = ln;
    #pragma unroll
    for (int o = 1; o < 64; o <<= 1) {
      int t = __shfl_up(s, o);
      if (tid >= o) s += t;
    }
    cum[tid + 1] = s;
    if (tid == 0) cum[0] = 0;
    if (tid == 63) wsi[WS_CNT] = s;
  }
  __syncthreads();
  if (tid <= NB) wsi[WS_CUM + tid] = cum[tid];
  int t = blockIdx.x * 256 + tid;   // grid 32 covers 8192
  int b = t >> 7, l = t & 127;
  int len = cum[b + 1] - cum[b];
  if (l < len) wsi[WS_ROWS + cum[b] + l] = t;
}

// softmax denominators per compacted row (full-K streaming pass)
__global__ __launch_bounds__(256) void k_srow(const int* __restrict__ clist,
                                              const float* __restrict__ edge,
                                              float* __restrict__ wsf) {
  const int* wsi = (const int*)wsf;
  int wid = threadIdx.x >> 6, lane = threadIdx.x & 63;
  int pos = blockIdx.x * 4 + wid;
  int count = wsi[WS_CNT];
  if (pos >= count) return;
  int row = wsi[WS_ROWS + pos];
  const float4* e4 = (const float4*)(edge + (long)clist[row] * NV);
  const float4* A4 = (const float4*)(wsf + WS_A);
  const float4* B4 = (const float4*)(wsf + WS_B);
  float sp = 0.f;
  for (int v = lane; v < NV / 4; v += 64) {
    float4 em = e4[v], a = A4[v], b = B4[v];
    sp += __expf(fmaf(a.x, em.x, (em.x > 0.f) ? b.x : 0.f));
    sp += __expf(fmaf(a.y, em.y, (em.y > 0.f) ? b.y : 0.f));
    sp += __expf(fmaf(a.z, em.z, (em.z > 0.f) ? b.z : 0.f));
    sp += __expf(fmaf(a.w, em.w, (em.w > 0.f) ? b.w : 0.f));
  }
  #pragma unroll
  for (int o = 32; o; o >>= 1) sp += __shfl_xor(sp, o);
  if (lane == 0) wsf[WS_S + pos] = sp;
}

// K-major MFMA GEMM: r5 structure (KR=128, 512 thr, register staging, single
// barrier/tile) + LDS metadata tables (no in-loop gather chains) + batch
// partitioning (all emits -> LDS sout) + g-major grid (XCD-shared wtg slices).
__global__ __launch_bounds__(512, 4) void k_main(const int* __restrict__ clist,
                                                 const int* __restrict__ clen,
                                                 const float* __restrict__ edge,
                                                 const float* __restrict__ wsf,
                                                 float* __restrict__ out) {
  __shared__ __align__(16) unsigned short ebuf[2][MT * KR];  // 16384 B (XOR-swizzled)
  __shared__ float cls[2][KR];                               //  1024 B
  __shared__ float sout[GMB][304];                           //  9728 B
  __shared__ int   rofs[MTOT];                               //  4096 B (clist[row]*NV)
  __shared__ int   bvt[MTOT];                                //  4096 B (batch or -1)
  __shared__ float sclv[MTOT];                               //  4096 B (1/(S*len))

  const int* wsi = (const int*)wsf;
  const unsigned short* wtg = (const unsigned short*)(wsf + WS_WTG);
  int tid = threadIdx.x;
  int kr = blockIdx.x % NKR, g = blockIdx.x / NKR;   // g-major: XCD shares wtg slice
  int v0 = kr * KR;
  int klen = NV - v0; if (klen > KR) klen = KR;
  int nch = (klen + 31) >> 5;
  int bs = g * GMB;
  int r0 = wsi[WS_CUM + bs], r1 = wsi[WS_CUM + bs + GMB];
  int nrows = r1 - r0;
  int ntiles = (nrows + MT - 1) >> 5;

  int wv = tid >> 6, lane = tid & 63;
  int q4 = lane >> 4, l15 = lane & 15;
  int nt0 = (wv * NTI) >> 3, nt1 = ((wv + 1) * NTI) >> 3;   // 2-3 n-tiles/wave

  // B-fragments: global loads issued first, drain during prologue
  bf16x8 bfrag[3][4] = {};
  #pragma unroll
  for (int j = 0; j < 3; ++j)
    #pragma unroll
    for (int c5 = 0; c5 < 4; ++c5)
      if (nt0 + j < nt1 && c5 < nch) {
        int n = (nt0 + j) * 16 + l15;
        bfrag[j][c5] = *(const bf16x8*)(const void*)&wtg[(long)n * WTGLD + v0 + c5 * 32 + q4 * 8];
      }

  // prologue staging: coeff slice, sout zero, row metadata tables
  for (int q = tid; q < 2 * KR; q += 512) {
    int a = q >> 7, k = q & (KR - 1);
    float val = 0.f;
    if (v0 + k < NV) val = wsf[(a ? WS_B : WS_A) + v0 + k];
    cls[a][k] = val;
  }
  for (int q = tid; q < GMB * 304; q += 512) ((float*)sout)[q] = 0.f;
  for (int i = tid; i < MTOT; i += 512) {
    int ro = 0, b = -1; float sc = 0.f;
    if (i < nrows) {
      int rowid = wsi[WS_ROWS + r0 + i];
      ro = clist[rowid] * NV;          // < 1e8, fits int
      b = rowid >> 7;
      float S = wsf[WS_S + r0 + i];
      int ln = clen[b];
      sc = 1.0f / (S * (float)(ln > 0 ? ln : 1));
    }
    rofs[i] = ro; bvt[i] = b; sclv[i] = sc;
  }
  __syncthreads();

  // staging slots: thread covers (rm_s, kf) and (rm_s+16, kf); 1024 slots
  int rm_s = tid >> 5;          // 0..15
  int kf = tid & 31;            // float4 column 0..31
  int kvalid = (kf * 4 < klen);
  int vkq = v0 + (kvalid ? kf * 4 : 0);

  float4 eld[2];
  int    vld[2];

  auto stage_load = [&](int tt, bool valid) {
    #pragma unroll
    for (int j = 0; j < 2; ++j) {
      vld[j] = 0;
      int i0 = tt * MT + rm_s + 16 * j;
      if (valid && kvalid && i0 < nrows) {
        eld[j] = *(const float4*)(edge + (long)rofs[i0] + vkq);
        vld[j] = 1;
      }
    }
  };

  auto stage_write = [&](int nb) {
    char* eb = (char*)&ebuf[nb][0];
    #pragma unroll
    for (int j = 0; j < 2; ++j) {
      ushort4 ev = make_ushort4(0, 0, 0, 0);
      if (vld[j]) {
        float4 a = *(const float4*)&cls[0][kf * 4];
        float4 b = *(const float4*)&cls[1][kf * 4];
        float4 em = eld[j];
        ev.x = f2bf(__expf(fmaf(a.x, em.x, (em.x > 0.f) ? b.x : 0.f)));
        ev.y = f2bf(__expf(fmaf(a.y, em.y, (em.y > 0.f) ? b.y : 0.f)));
        ev.z = f2bf(__expf(fmaf(a.z, em.z, (em.z > 0.f) ? b.z : 0.f)));
        ev.w = f2bf(__expf(fmaf(a.w, em.w, (em.w > 0.f) ? b.w : 0.f)));
      }
      int row = rm_s + 16 * j;
      int off = ((row << 8) + (kf << 3)) ^ ((row & 7) << 4);
      *(ushort4*)(eb + off) = ev;
    }
  };

  // per-lane batch-run accumulator (rows sorted by batch)
  int curb = -1;
  float rs0 = 0.f, rs1 = 0.f, rs2 = 0.f;
  auto emit = [&](int b) {
    if (b < 0) return;
    int rel = b - bs;   // in [0, GMB) by batch partitioning
    #pragma unroll
    for (int j = 0; j < 3; ++j) {
      if (nt0 + j < nt1) {
        int n = (nt0 + j) * 16 + l15;
        if (n < ND) {
          float v = (j == 0) ? rs0 : (j == 1) ? rs1 : rs2;
          atomicAdd(&sout[rel][n], v);
        }
      }
    }
  };

  if (ntiles > 0) {
    stage_load(0, true);
    stage_write(0);
    __syncthreads();

    for (int t = 0; t < ntiles; ++t) {
      int cur = t & 1;
      // issue next tile's loads (addresses from LDS table -> no gather chain)
      stage_load(t + 1, t + 1 < ntiles);

      // MFMA on current buffer
      f32x4 acc[2][3] = {};
      const char* eb = (const char*)&ebuf[cur][0];
      #pragma unroll
      for (int c5 = 0; c5 < 4; ++c5) {
        if (c5 < nch) {
          int kb2 = (c5 * 32 + q4 * 8) << 1;
          int off0 = ((l15 << 8) + kb2) ^ ((l15 & 7) << 4);
          int off1 = (((16 + l15) << 8) + kb2) ^ ((l15 & 7) << 4);
          bf16x8 a0 = *(const bf16x8*)(const void*)(eb + off0);
          bf16x8 a1 = *(const bf16x8*)(const void*)(eb + off1);
          #pragma unroll
          for (int j = 0; j < 3; ++j) {
            if (nt0 + j < nt1) {
              acc[0][j] = __builtin_amdgcn_mfma_f32_16x16x32_bf16(a0, bfrag[j][c5], acc[0][j], 0, 0, 0);
              acc[1][j] = __builtin_amdgcn_mfma_f32_16x16x32_bf16(a1, bfrag[j][c5], acc[1][j], 0, 0, 0);
            }
          }
        }
      }

      // exp + pack next tile into the other buffer
      stage_write(cur ^ 1);

      // fold current tile into per-lane batch runs (table lookups, no VMEM)
      #pragma unroll
      for (int ms = 0; ms < 2; ++ms)
        #pragma unroll
        for (int r = 0; r < 4; ++r) {
          int m = ms * 16 + q4 * 4 + r;
          int i = t * MT + m;
          int b = bvt[i];
          if (b >= 0) {
            float sc = sclv[i];
            if (b != curb) {
              emit(curb);
              curb = b; rs0 = rs1 = rs2 = 0.f;
            }
            rs0 += acc[ms][0][r] * sc;
            rs1 += acc[ms][1][r] * sc;
            rs2 += acc[ms][2][r] * sc;
          }
        }

      __syncthreads();
    }
    emit(curb);
  }
  __syncthreads();

  // final flush: sout -> out
  for (int q = tid; q < GMB * 304; q += 512) {
    int s = q / 304, n = q - s * 304;
    float v = sout[s][n];
    if (n < ND && v != 0.f) atomicAdd(&out[(bs + s) * ND + n], v);
  }
}

extern "C" void kernel_launch(void* const* d_in, const int* in_sizes, int n_in,
                              void* d_out, int out_size, void* d_ws, size_t ws_size,
                              hipStream_t stream) {
  const int*   clist = (const int*)d_in[0];
  const int*   clen  = (const int*)d_in[1];
  const float* embed = (const float*)d_in[2];
  const float* cw    = (const float*)d_in[3];
  const float* edge  = (const float*)d_in[4];
  const float* aff   = (const float*)d_in[5];
  const float* lam   = (const float*)d_in[6];
  float* out = (float*)d_out;
  float* wsf = (float*)d_ws;
  int*   wsi = (int*)d_ws;

  hipLaunchKernelGGL(k_init,    dim3(77),          dim3(256), 0, stream, out, wsf);
  hipLaunchKernelGGL(k_context, dim3(NB * CSL),    dim3(320), 0, stream, clist, clen, embed, wsf);
  hipLaunchKernelGGL(k_cn,      dim3(1),           dim3(320), 0, stream, wsf);
  hipLaunchKernelGGL(k_cos,     dim3(NV / 4),      dim3(256), 0, stream, cw, lam, aff, wsf);
  hipLaunchKernelGGL(k_wt,      dim3(WTGLD / 64),  dim3(256), 0, stream, cw, wsf);
  hipLaunchKernelGGL(k_compact, dim3(32),          dim3(256), 0, stream, clen, wsi);
  hipLaunchKernelGGL(k_srow,    dim3(NB * NL / 4), dim3(256), 0, stream, clist, edge, wsf);
  hipLaunchKernelGGL(k_main,    dim3(NKR * 8),     dim3(512), 0, stream,
                     clist, clen, edge, wsf, out);
}

// Round 12
// 181.151 us; speedup vs baseline: 2.2021x; 2.2021x over previous
//
#include <hip/hip_runtime.h>
#include <math.h>

#define NV 10000
#define ND 300
#define NB 64
#define NL 128
#define CFv 5.0f
#define EPSV 1e-8f

// ws float-index layout (~6.3 MB used; ws proven >= 1.6 GB by harness fill)
#define WS_CTX   0        // 300 floats
#define WS_CN    300      // 1 float
#define WS_CNT   301      // 1 int (active-row count)
#define WS_A     320      // 10000 floats: CF*lam*cos
#define WS_B     10320    // 10000 floats: CF*(1-lam)*aff
#define WS_ROWS  20320    // 8192 ints (compacted, SORTED active row ids b*128+l)
#define WS_S     28512    // 8192 floats (softmax denominators)
#define WS_WTG   36704    // bf16 WtG[304][10112] (byte off 146816, 16B aligned)

// k_main config
#define KR    128         // K-slice per block
#define WTGLD 10112       // padded WtG row length (= 79*128)
#define NKR   79          // ceil(10000/128)
#define GMG   6           // M-groups per K-slice (contiguous chunks)
#define NTI   19          // 19 n-tiles of 16 cover 304
#define MT    32          // rows per M-tile
#define SOB   16          // sout batch slots

typedef __attribute__((ext_vector_type(8))) __bf16 bf16x8;
typedef __attribute__((ext_vector_type(4))) float f32x4;

static __device__ __forceinline__ unsigned short f2bf(float x) {
  union { float f; unsigned u; } v; v.f = x;
  unsigned r = v.u + 0x7fffu + ((v.u >> 16) & 1u);
  return (unsigned short)(r >> 16);
}

__global__ __launch_bounds__(256) void k_init(float* __restrict__ out, float* __restrict__ wsf) {
  int g = blockIdx.x * 256 + threadIdx.x;
  if (g < NB * ND) out[g] = 0.f;
  if (g < 302) wsf[g] = 0.f;
}

#define CSL 4
__global__ __launch_bounds__(320) void k_context(const int* __restrict__ clist,
                                                 const int* __restrict__ clen,
                                                 const float* __restrict__ embed,
                                                 float* __restrict__ wsf) {
  __shared__ int kl[NL];
  int b = blockIdx.x / CSL, sl = blockIdx.x % CSL;
  int d = threadIdx.x;
  int len = clen[b];
  if (d < NL) kl[d] = clist[b * NL + d];
  __syncthreads();
  if (d >= ND) return;
  float acc = 0.f;
  for (int l = sl; l < len; l += CSL)
    acc += embed[(long)kl[l] * ND + d];
  float dn = (float)(len > 0 ? len : 1);
  atomicAdd(&wsf[WS_CTX + d], acc * (1.0f / NB) / dn);
}

__global__ __launch_bounds__(320) void k_cn(float* __restrict__ wsf) {
  __shared__ float red[5];
  int t = threadIdx.x;
  float x = (t < ND) ? wsf[WS_CTX + t] : 0.f;
  float s = x * x;
  #pragma unroll
  for (int o = 32; o; o >>= 1) s += __shfl_xor(s, o);
  if ((t & 63) == 0) red[t >> 6] = s;
  __syncthreads();
  if (t == 0) {
    float tot = 0.f;
    #pragma unroll
    for (int i = 0; i < 5; ++i) tot += red[i];
    wsf[WS_CN] = sqrtf(tot);
  }
}

// per-concept |cos| then fused constants A = CF*lam*cos, B = CF*(1-lam)*aff
__global__ __launch_bounds__(256) void k_cos(const float* __restrict__ cw,
                                             const float* __restrict__ lam,
                                             const float* __restrict__ aff,
                                             float* __restrict__ wsf) {
  int wid = threadIdx.x >> 6, lane = threadIdx.x & 63;
  int v = blockIdx.x * 4 + wid;
  const float* row = cw + (long)v * ND;
  float dot = 0.f, rn2 = 0.f;
  for (int d = lane; d < ND; d += 64) {
    float w = row[d], c = wsf[WS_CTX + d];
    dot += w * c;
    rn2 += w * w;
  }
  #pragma unroll
  for (int o = 32; o; o >>= 1) { dot += __shfl_xor(dot, o); rn2 += __shfl_xor(rn2, o); }
  if (lane == 0) {
    float cn = wsf[WS_CN];
    float cosv = fabsf(dot) / fmaxf(cn * sqrtf(rn2), EPSV);
    float lv = lam[v];
    wsf[WS_A + v] = CFv * lv * cosv;
    wsf[WS_B + v] = CFv * (1.f - lv) * aff[v];
  }
}

// transpose concept_w -> bf16 WtG[304][WTGLD] in ws (zero-padded rows/cols)
__global__ __launch_bounds__(256) void k_wt(const float* __restrict__ cw, float* __restrict__ wsf) {
  __shared__ unsigned short T[304][68];
  int tid = threadIdx.x;
  int v0 = blockIdx.x * 64;
  for (int q = tid; q < 304 * 68 / 2; q += 256) ((unsigned*)&T[0][0])[q] = 0u;
  __syncthreads();
  const float4* cw4 = (const float4*)cw;
  for (int q = tid; q < 64 * 75; q += 256) {
    int r = q / 75, p = q - r * 75;
    int v = v0 + r;
    if (v < NV) {
      float4 w = cw4[(long)v * 75 + p];
      T[4 * p + 0][r] = f2bf(w.x);
      T[4 * p + 1][r] = f2bf(w.y);
      T[4 * p + 2][r] = f2bf(w.z);
      T[4 * p + 3][r] = f2bf(w.w);
    }
  }
  __syncthreads();
  unsigned short* wtg = (unsigned short*)(wsf + WS_WTG);
  for (int q = tid; q < 304 * 16; q += 256) {
    int n = q >> 4, rp = q & 15;
    *(ushort4*)&wtg[(long)n * WTGLD + v0 + 4 * rp] = *(const ushort4*)&T[n][4 * rp];
  }
}

// deterministic, SORTED compaction via per-batch prefix sums
__global__ __launch_bounds__(256) void k_compact(const int* __restrict__ clen, int* __restrict__ wsi) {
  __shared__ int cum[NB + 1];
  int tid = threadIdx.x;
  if (tid == 0) {
    int c = 0;
    for (int b = 0; b < NB; ++b) {
      cum[b] = c;
      int ln = clen[b]; if (ln < 0) ln = 0; if (ln > NL) ln = NL;
      c += ln;
    }
    cum[NB] = c;
    wsi[WS_CNT] = c;
  }
  __syncthreads();
  for (int t = tid; t < NB * NL; t += 256) {
    int b = t >> 7, l = t & 127;
    int len = cum[b + 1] - cum[b];
    if (l < len) wsi[WS_ROWS + cum[b] + l] = t;
  }
}

// softmax denominators per compacted row (full-K streaming pass)
__global__ __launch_bounds__(256) void k_srow(const int* __restrict__ clist,
                                              const float* __restrict__ edge,
                                              float* __restrict__ wsf) {
  const int* wsi = (const int*)wsf;
  int wid = threadIdx.x >> 6, lane = threadIdx.x & 63;
  int pos = blockIdx.x * 4 + wid;
  int count = wsi[WS_CNT];
  if (pos >= count) return;
  int row = wsi[WS_ROWS + pos];
  const float4* e4 = (const float4*)(edge + (long)clist[row] * NV);
  const float4* A4 = (const float4*)(wsf + WS_A);
  const float4* B4 = (const float4*)(wsf + WS_B);
  float sp = 0.f;
  for (int v = lane; v < NV / 4; v += 64) {
    float4 em = e4[v], a = A4[v], b = B4[v];
    sp += __expf(fmaf(a.x, em.x, (em.x > 0.f) ? b.x : 0.f));
    sp += __expf(fmaf(a.y, em.y, (em.y > 0.f) ? b.y : 0.f));
    sp += __expf(fmaf(a.z, em.z, (em.z > 0.f) ? b.z : 0.f));
    sp += __expf(fmaf(a.w, em.w, (em.w > 0.f) ? b.w : 0.f));
  }
  #pragma unroll
  for (int o = 32; o; o >>= 1) sp += __shfl_xor(sp, o);
  if (lane == 0) wsf[WS_S + pos] = sp;
}

// K-major MFMA GEMM: block owns K-slice [v0,v0+klen), B-fragments in registers
// (loaded once from pre-transposed bf16 WtG), contiguous M-chunk, LDS sout.
__global__ __launch_bounds__(512, 4) void k_main(const int* __restrict__ clist,
                                                 const int* __restrict__ clen,
                                                 const float* __restrict__ edge,
                                                 const float* __restrict__ wsf,
                                                 float* __restrict__ out) {
  __shared__ unsigned short ebuf[2][MT * KR];   // 16384 B (XOR-swizzled)
  __shared__ float cls[2][KR];                  //  1024 B
  __shared__ float sout[SOB][304];              // 19456 B
  __shared__ int   rb_s[2][MT];
  __shared__ float scl_s[2][MT];

  const int* wsi = (const int*)wsf;
  const unsigned short* wtg = (const unsigned short*)(wsf + WS_WTG);
  int tid = threadIdx.x;
  int count = wsi[WS_CNT];
  int Mtiles = (count + MT - 1) / MT;
  int kr = blockIdx.x / GMG, g = blockIdx.x % GMG;
  int v0 = kr * KR;
  int klen = NV - v0; if (klen > KR) klen = KR;
  int nch = (klen + 31) >> 5;
  int tpg = (Mtiles + GMG - 1) / GMG;
  int mt0 = g * tpg;
  int mt1 = min(mt0 + tpg, Mtiles);

  int b0 = 0;
  {
    int r0c = mt0 * MT;
    if (r0c < count) b0 = wsi[WS_ROWS + r0c] >> 7;
  }

  // stage A/B slice + zero sout
  for (int q = tid; q < 2 * KR; q += 512) {
    int a = q >> 7, k = q & (KR - 1);
    float val = 0.f;
    if (v0 + k < NV) val = wsf[(a ? WS_B : WS_A) + v0 + k];
    cls[a][k] = val;
  }
  for (int q = tid; q < SOB * 304; q += 512) ((float*)sout)[q] = 0.f;

  int wv = tid >> 6, lane = tid & 63;
  int q4 = lane >> 4, l15 = lane & 15;
  int nt0 = (wv * NTI) >> 3, nt1 = ((wv + 1) * NTI) >> 3;

  // B-fragments direct from WtG (coalesced bf16x8 per fragment)
  bf16x8 bfrag[3][4] = {};
  #pragma unroll
  for (int j = 0; j < 3; ++j)
    #pragma unroll
    for (int c5 = 0; c5 < 4; ++c5)
      if (nt0 + j < nt1 && c5 < nch) {
        int n = (nt0 + j) * 16 + l15;
        bfrag[j][c5] = *(const bf16x8*)(const void*)&wtg[(long)n * WTGLD + v0 + c5 * 32 + q4 * 8];
      }

  // BARRIER: cls/sout staged above are read by stage_write/emit below
  __syncthreads();

  // staging: slot tid+512j -> (row rm, 4 k's); exactly 1024 slots
  float4 eld[2];
  int    vld[2];
  int    m_row; float m_scl;

  auto stage_load = [&](int mtx, bool valid) {
    int r0 = mtx * MT;
    #pragma unroll
    for (int j = 0; j < 2; ++j) {
      vld[j] = 0;
      int q = tid + j * 512;
      int rm = q >> 5, k = (q & 31) * 4;
      int pos = r0 + rm;
      if (valid && pos < count && k < klen) {
        int rowid = wsi[WS_ROWS + pos];
        eld[j] = *(const float4*)(edge + (long)clist[rowid] * NV + v0 + k);
        vld[j] = 1;
      }
    }
    m_row = -1; m_scl = 0.f;
    if (tid < MT) {
      int pos = r0 + tid;
      if (valid && pos < count) {
        int rowid = wsi[WS_ROWS + pos];
        float S = wsf[WS_S + pos];
        int ln = clen[rowid >> 7];
        m_row = rowid;
        m_scl = 1.0f / (S * (float)(ln > 0 ? ln : 1));
      }
    }
  };

  auto stage_write = [&](int nb) {
    char* eb = (char*)&ebuf[nb][0];
    #pragma unroll
    for (int j = 0; j < 2; ++j) {
      int q = tid + j * 512;
      int rm = q >> 5, k = (q & 31) * 4;
      ushort4 ev = make_ushort4(0, 0, 0, 0);
      if (vld[j]) {
        float4 a = *(const float4*)&cls[0][k];
        float4 b = *(const float4*)&cls[1][k];
        float4 em = eld[j];
        ev.x = f2bf(__expf(fmaf(a.x, em.x, (em.x > 0.f) ? b.x : 0.f)));
        ev.y = f2bf(__expf(fmaf(a.y, em.y, (em.y > 0.f) ? b.y : 0.f)));
        ev.z = f2bf(__expf(fmaf(a.z, em.z, (em.z > 0.f) ? b.z : 0.f)));
        ev.w = f2bf(__expf(fmaf(a.w, em.w, (em.w > 0.f) ? b.w : 0.f)));
      }
      int off = (rm << 8) + (k << 1);
      off ^= (rm & 7) << 4;
      *(ushort4*)(eb + off) = ev;
    }
    if (tid < MT) { rb_s[nb][tid] = m_row; scl_s[nb][tid] = m_scl; }
  };

  // per-lane batch-run accumulator (rows sorted by batch)
  int curb = -1;
  float rs0 = 0.f, rs1 = 0.f, rs2 = 0.f;
  auto emit = [&](int b, float s0, float s1, float s2) {
    if (b < 0) return;
    #pragma unroll
    for (int j = 0; j < 3; ++j) {
      if (nt0 + j < nt1) {
        int n = (nt0 + j) * 16 + l15;
        if (n < ND) {
          float v = (j == 0) ? s0 : (j == 1) ? s1 : s2;
          int rel = b - b0;
          if (rel >= 0 && rel < SOB) atomicAdd(&sout[rel][n], v);
          else atomicAdd(&out[b * ND + n], v);
        }
      }
    }
  };

  if (mt0 < mt1) {
    stage_load(mt0, true);
    stage_write(0);
    __syncthreads();

    int cb = 0;
    for (int mt = mt0; mt < mt1; ++mt) {
      stage_load(mt + 1, mt + 1 < mt1);

      f32x4 acc[2][3] = {};
      const char* eb = (const char*)&ebuf[cb][0];
      #pragma unroll
      for (int c5 = 0; c5 < 4; ++c5) {
        if (c5 < nch) {
          int kb2 = (c5 * 32 + q4 * 8) << 1;
          int off0 = ((l15 << 8) + kb2) ^ ((l15 & 7) << 4);
          int off1 = (((16 + l15) << 8) + kb2) ^ ((l15 & 7) << 4);
          bf16x8 a0 = *(const bf16x8*)(const void*)(eb + off0);
          bf16x8 a1 = *(const bf16x8*)(const void*)(eb + off1);
          #pragma unroll
          for (int j = 0; j < 3; ++j) {
            if (nt0 + j < nt1) {
              acc[0][j] = __builtin_amdgcn_mfma_f32_16x16x32_bf16(a0, bfrag[j][c5], acc[0][j], 0, 0, 0);
              acc[1][j] = __builtin_amdgcn_mfma_f32_16x16x32_bf16(a1, bfrag[j][c5], acc[1][j], 0, 0, 0);
            }
          }
        }
      }

      stage_write(cb ^ 1);

      // fold current tile into per-lane runs (rows ascending: ms then r)
      #pragma unroll
      for (int ms = 0; ms < 2; ++ms)
        #pragma unroll
        for (int r = 0; r < 4; ++r) {
          int m = ms * 16 + q4 * 4 + r;
          int row = rb_s[cb][m];
          if (row >= 0) {
            int b = row >> 7;
            float sc = scl_s[cb][m];
            if (b != curb) {
              emit(curb, rs0, rs1, rs2);
              curb = b; rs0 = rs1 = rs2 = 0.f;
            }
            rs0 += acc[ms][0][r] * sc;
            rs1 += acc[ms][1][r] * sc;
            rs2 += acc[ms][2][r] * sc;
          }
        }

      __syncthreads();
      cb ^= 1;
    }
    emit(curb, rs0, rs1, rs2);
  }
  __syncthreads();

  // final emission: sout -> out (skip zeros)
  for (int q = tid; q < SOB * 304; q += 512) {
    int s = q / 304, n = q - s * 304;
    float v = sout[s][n];
    if (n < ND && v != 0.f) {
      int b = b0 + s;
      if (b < NB) atomicAdd(&out[b * ND + n], v);
    }
  }
}

extern "C" void kernel_launch(void* const* d_in, const int* in_sizes, int n_in,
                              void* d_out, int out_size, void* d_ws, size_t ws_size,
                              hipStream_t stream) {
  const int*   clist = (const int*)d_in[0];
  const int*   clen  = (const int*)d_in[1];
  const float* embed = (const float*)d_in[2];
  const float* cw    = (const float*)d_in[3];
  const float* edge  = (const float*)d_in[4];
  const float* aff   = (const float*)d_in[5];
  const float* lam   = (const float*)d_in[6];
  float* out = (float*)d_out;
  float* wsf = (float*)d_ws;
  int*   wsi = (int*)d_ws;

  hipLaunchKernelGGL(k_init,    dim3(77),          dim3(256), 0, stream, out, wsf);
  hipLaunchKernelGGL(k_context, dim3(NB * CSL),    dim3(320), 0, stream, clist, clen, embed, wsf);
  hipLaunchKernelGGL(k_cn,      dim3(1),           dim3(320), 0, stream, wsf);
  hipLaunchKernelGGL(k_cos,     dim3(NV / 4),      dim3(256), 0, stream, cw, lam, aff, wsf);
  hipLaunchKernelGGL(k_wt,      dim3(WTGLD / 64),  dim3(256), 0, stream, cw, wsf);
  hipLaunchKernelGGL(k_compact, dim3(1),           dim3(256), 0, stream, clen, wsi);
  hipLaunchKernelGGL(k_srow,    dim3(NB * NL / 4), dim3(256), 0, stream, clist, edge, wsf);
  hipLaunchKernelGGL(k_main,    dim3(NKR * GMG),   dim3(512), 0, stream,
                     clist, clen, edge, wsf, out);
}